// Round 11
// baseline (34.386 us; speedup 1.0000x reference)
//
#include <hip/hip_runtime.h>

constexpr int CODE_LEN = 1024;
constexpr int INFO_LEN = 512;
constexpr int BATCH    = 2048;
constexpr int ITERS    = 5;
#define CLIPV 15.0f

// f(a,b) = sign(a)*sign(b)*min(|a|,|b|) -- forced 3-inst codegen.
__device__ __forceinline__ float fop(float a, float b) {
    unsigned x; float m, r;
    asm("v_xor_b32 %0, %1, %2" : "=v"(x) : "v"(a), "v"(b));
    asm("v_min_f32 %0, |%1|, |%2|" : "=v"(m) : "v"(a), "v"(b));
    asm("v_and_or_b32 %0, %1, %2, %3" : "=v"(r) : "v"(x), "s"(0x80000000u), "v"(m));
    return r;
}
__device__ __forceinline__ float clipf(float x) {
    return __builtin_amdgcn_fmed3f(x, -CLIPV, CLIPV);
}

// ---------------------------------------------------------------------------
// R7-R10 scheme: position p at (wave,lane,slot) per layout group; butterflies
// between register slots (select-free); conversions move the one boundary
// array via LDS (CONV_W in-wave, no barrier; CONV_X cross-wave, 1 barrier).
// R11: ILP-2 -- each block decodes TWO codewords (2b, 2b+1), interleaved at
// step granularity. Barriers/CONV_X serve both codewords (barrier events per
// codeword halve); each wave carries two independent dependence chains (in-
// wave latency hiding doubles). Per-SIMD issue unchanged -> pure stall cut.
// RK/fr are codeword-independent (same info_idx) -> shared.
// ---------------------------------------------------------------------------

#define RSTEP0(A, B) do { \
    float bu0=(B)[0], bl0=(B)[1], bu1=(B)[2], bl1=(B)[3]; \
    (B)[0]=fop((A)[0], bl0+(A)[1]); \
    (B)[1]=clipf(fop((A)[0], bu0)+(A)[1]); \
    (B)[2]=fop((A)[2], bl1+(A)[3]); \
    (B)[3]=clipf(fop((A)[2], bu1)+(A)[3]); } while(0)
#define RSTEP1(A, B) do { \
    float bu0=(B)[0], bl0=(B)[2], bu1=(B)[1], bl1=(B)[3]; \
    (B)[0]=fop((A)[0], bl0+(A)[2]); \
    (B)[2]=clipf(fop((A)[0], bu0)+(A)[2]); \
    (B)[1]=fop((A)[1], bl1+(A)[3]); \
    (B)[3]=clipf(fop((A)[1], bu1)+(A)[3]); } while(0)
#define LSTEP0(A, B) do { \
    float au0=(A)[0], al0=(A)[1], au1=(A)[2], al1=(A)[3]; \
    (A)[0]=fop((B)[0], (B)[1]+al0); \
    (A)[1]=clipf(fop(au0, (B)[0])+(B)[1]); \
    (A)[2]=fop((B)[2], (B)[3]+al1); \
    (A)[3]=clipf(fop(au1, (B)[2])+(B)[3]); } while(0)
#define LSTEP1(A, B) do { \
    float au0=(A)[0], al0=(A)[2], au1=(A)[1], al1=(A)[3]; \
    (A)[0]=fop((B)[0], (B)[2]+al0); \
    (A)[2]=clipf(fop(au0, (B)[0])+(B)[2]); \
    (A)[1]=fop((B)[1], (B)[3]+al1); \
    (A)[3]=clipf(fop(au1, (B)[1])+(B)[3]); } while(0)
// stage-9 left step: B = rx (UNclipped) -> keep u-clip
#define LSTEP1C(A, B) do { \
    float au0=(A)[0], al0=(A)[2], au1=(A)[1], al1=(A)[3]; \
    (A)[0]=clipf(fop((B)[0], (B)[2]+al0)); \
    (A)[2]=clipf(fop(au0, (B)[0])+(B)[2]); \
    (A)[1]=clipf(fop((B)[1], (B)[3]+al1)); \
    (A)[3]=clipf(fop(au1, (B)[1])+(B)[3]); } while(0)
// iteration-0 right steps (l == 0): u' = fop(r_u, r_l), l' = r_l
#define RSTEP0Z(A, B) do { \
    (B)[0]=fop((A)[0], (A)[1]); (B)[1]=(A)[1]; \
    (B)[2]=fop((A)[2], (A)[3]); (B)[3]=(A)[3]; } while(0)
#define RSTEP1Z(A, B) do { \
    (B)[0]=fop((A)[0], (A)[2]); (B)[2]=(A)[2]; \
    (B)[1]=fop((A)[1], (A)[3]); (B)[3]=(A)[3]; } while(0)

// LDS-only barrier: no vmcnt drain (emit stores stay in flight).
#define XBAR() do { \
    asm volatile("s_waitcnt lgkmcnt(0)" ::: "memory"); \
    __builtin_amdgcn_s_barrier(); \
    __builtin_amdgcn_sched_barrier(0); } while(0)

// in-wave conversion (per codeword buffer WBp)
#define CONV_W(arr, WBp, WB_, RB_) do { \
    *(float4*)&(WBp)[WB_] = make_float4((arr)[0], (arr)[1], (arr)[2], (arr)[3]); \
    const float* rp_ = &(WBp)[RB_]; \
    float c0_ = rp_[0], c1_ = rp_[64], c2_ = rp_[128], c3_ = rp_[192]; \
    (arr)[0]=c0_; (arr)[1]=c1_; (arr)[2]=c2_; (arr)[3]=c3_; } while(0)

// tuple-permute by m (write side of CONV_X)
#define XPERM(arr, U0_, U1_, U2_, U3_) \
    float T0_ = mb0 ? (arr)[1] : (arr)[0]; \
    float T1_ = mb0 ? (arr)[0] : (arr)[1]; \
    float T2_ = mb0 ? (arr)[3] : (arr)[2]; \
    float T3_ = mb0 ? (arr)[2] : (arr)[3]; \
    float U0_ = mb1 ? T2_ : T0_; \
    float U1_ = mb1 ? T3_ : T1_; \
    float U2_ = mb1 ? T0_ : T2_; \
    float U3_ = mb1 ? T1_ : T3_;

// cross-wave conversion for BOTH codewords, ONE barrier.
// cwB region at +1024 words inside XG (2048-word buffer).
#define CONV_X2(arrA, arrB, XG) do { \
    { XPERM(arrA, a0_, a1_, a2_, a3_) \
      *(float4*)&(XG)[wX] = make_float4(a0_, a1_, a2_, a3_); } \
    { XPERM(arrB, b0_, b1_, b2_, b3_) \
      *(float4*)&(XG)[wX + 1024] = make_float4(b0_, b1_, b2_, b3_); } \
    XBAR(); \
    { const float* xp_ = &(XG)[rX]; \
      float c0_ = xp_[0], c1_ = xp_[256], c2_ = xp_[512], c3_ = xp_[768]; \
      (arrA)[0]=c0_; (arrA)[1]=c1_; (arrA)[2]=c2_; (arrA)[3]=c3_; } \
    { const float* xp_ = &(XG)[rX + 1024]; \
      float c0_ = xp_[0], c1_ = xp_[256], c2_ = xp_[512], c3_ = xp_[768]; \
      (arrB)[0]=c0_; (arrB)[1]=c1_; (arrB)[2]=c2_; (arrB)[3]=c3_; } } while(0)

__global__ __launch_bounds__(256, 2) void polar_bp_r11(const float* __restrict__ rx,
                                                       const int* __restrict__ info,
                                                       float* __restrict__ out) {
    __shared__ int   RK[CODE_LEN];     // rank table, L0 flat order (shared A/B)
    __shared__ float WBA[CODE_LEN];    // in-wave conv scratch, codeword A
    __shared__ float WBB[CODE_LEN];    // in-wave conv scratch, codeword B
    __shared__ float XG0[2 * CODE_LEN];// cross-wave buffers (alternating gens)
    __shared__ float XG1[2 * CODE_LEN];

    const int t = threadIdx.x;
    const int b = blockIdx.x;

    // RK[L0-flat] = rank or -1. flat(p) = p10 | p76<<2 | p54<<4 | p32<<6 | p98<<8
    *(int4*)&RK[t * 4] = make_int4(-1, -1, -1, -1);
    __syncthreads();
#pragma unroll
    for (int k = 0; k < 2; ++k) {
        int kk = t + 256 * k;
        int p  = info[kk];
        int fl = (p & 3) | (((p >> 6) & 3) << 2) | (((p >> 4) & 3) << 4)
               | (((p >> 2) & 3) << 6) | (((p >> 8) & 3) << 8);
        RK[fl] = kk;
    }
    __syncthreads();

    // ---- precomputed conversion bases (dword indices, iteration-invariant) ----
    const int l6 = t & 63;
    const int w  = t >> 6;
    const int wbase = w * 256;
    const int wW4 = wbase + 4 * l6;
    const int rW4 = wbase + 4 * (l6 & 15) + ((l6 >> 4) & 3);
    const int wW2 = wbase + 4 * ((l6 & 3) | (((l6 >> 4) & 3) << 2) | (((l6 >> 2) & 3) << 4));
    const int rW2 = wbase + 4 * ((l6 & 3) | (((l6 >> 4) & 3) << 2)) + ((l6 >> 2) & 3);
    const int wW0 = wbase + 4 * (((l6 >> 2) & 15) | ((l6 & 3) << 4));
    const int rW0 = wbase + 4 * ((l6 >> 2) & 15) + (l6 & 3);
    const int  mX  = (l6 >> 3) & 3;
    const bool mb0 = (l6 & 8)  != 0;
    const bool mb1 = (l6 & 16) != 0;
    const int  wX  = 4 * l6 + 256 * w;
    const int  rX  = 4 * l6 + (w ^ mX);

    // ---- frozen vector (shared across codewords) ----
    float fr[4];
    {
        int4 rkv = *(const int4*)&RK[t * 4];
        fr[0] = rkv.x < 0 ? CLIPV : 0.f;  fr[1] = rkv.y < 0 ? CLIPV : 0.f;
        fr[2] = rkv.z < 0 ? CLIPV : 0.f;  fr[3] = rkv.w < 0 ? CLIPV : 0.f;
    }

    float SA[10][4], SB[10][4];
    // rx -> S[9] in L4 order: p = e*256 + t76*64 + t10*16 + t32*4 + t54
    {
        const int idx = ((t >> 6) & 3) * 64 + (t & 3) * 16
                      + ((t >> 2) & 3) * 4 + ((t >> 4) & 3);
        const float* rxa = rx + (size_t)(2 * b) * CODE_LEN + idx;
        const float* rxb = rxa + CODE_LEN;
        SA[9][0] = rxa[0];   SA[9][1] = rxa[256];
        SA[9][2] = rxa[512]; SA[9][3] = rxa[768];
        SB[9][0] = rxb[0];   SB[9][1] = rxb[256];
        SB[9][2] = rxb[512]; SB[9][3] = rxb[768];
    }

    // ===== iteration-0 RIGHT pass, peeled: all left arrays are zero =====
    RSTEP0Z(fr, SA[0]);        RSTEP0Z(fr, SB[0]);
    RSTEP1Z(SA[0], SA[1]);     RSTEP1Z(SB[0], SB[1]);
    CONV_W(SA[1], WBA, wW4, rW4);  CONV_W(SB[1], WBB, wW4, rW4);
    RSTEP0Z(SA[1], SA[2]);     RSTEP0Z(SB[1], SB[2]);
    RSTEP1Z(SA[2], SA[3]);     RSTEP1Z(SB[2], SB[3]);
    CONV_W(SA[3], WBA, wW2, rW2);  CONV_W(SB[3], WBB, wW2, rW2);
    RSTEP0Z(SA[3], SA[4]);     RSTEP0Z(SB[3], SB[4]);
    RSTEP1Z(SA[4], SA[5]);     RSTEP1Z(SB[4], SB[5]);
    CONV_W(SA[5], WBA, wW0, rW0);  CONV_W(SB[5], WBB, wW0, rW0);
    RSTEP0Z(SA[5], SA[6]);     RSTEP0Z(SB[5], SB[6]);
    RSTEP1Z(SA[6], SA[7]);     RSTEP1Z(SB[6], SB[7]);
    CONV_X2(SA[7], SB[7], XG0);            // (barrier)
    RSTEP0Z(SA[7], SA[8]);     RSTEP0Z(SB[7], SB[8]);

    float vA0, vA1, vA2, vA3, vB0, vB1, vB2, vB3;
    float* ob = out + (size_t)(2 * b) * INFO_LEN;   // codeword A row; B at +512
    const size_t obstride = (size_t)BATCH * INFO_LEN;

#pragma unroll 1
    for (int it = 0; it < ITERS; ++it) {
        // ===================== LEFT pass (s = 9..0) ======================
        LSTEP1C(SA[8], SA[9]);     LSTEP1C(SB[8], SB[9]);
        LSTEP0(SA[7], SA[8]);      LSTEP0(SB[7], SB[8]);
        CONV_X2(SA[7], SB[7], XG1);        // (barrier)
        LSTEP1(SA[6], SA[7]);      LSTEP1(SB[6], SB[7]);
        LSTEP0(SA[5], SA[6]);      LSTEP0(SB[5], SB[6]);
        CONV_W(SA[5], WBA, wW0, rW0);  CONV_W(SB[5], WBB, wW0, rW0);
        LSTEP1(SA[4], SA[5]);      LSTEP1(SB[4], SB[5]);
        LSTEP0(SA[3], SA[4]);      LSTEP0(SB[3], SB[4]);
        CONV_W(SA[3], WBA, wW2, rW2);  CONV_W(SB[3], WBB, wW2, rW2);
        LSTEP1(SA[2], SA[3]);      LSTEP1(SB[2], SB[3]);
        LSTEP0(SA[1], SA[2]);      LSTEP0(SB[1], SB[2]);
        CONV_W(SA[1], WBA, wW4, rW4);  CONV_W(SB[1], WBB, wW4, rW4);
        LSTEP1(SA[0], SA[1]);      LSTEP1(SB[0], SB[1]);
        // s0: emit left[0] at info positions (right[0] = 0 there), L0 order
        vA0 = fop(SA[0][0], SA[0][1] + fr[1]);
        vA1 = clipf(fop(fr[0], SA[0][0]) + SA[0][1]);
        vA2 = fop(SA[0][2], SA[0][3] + fr[3]);
        vA3 = clipf(fop(fr[2], SA[0][2]) + SA[0][3]);
        vB0 = fop(SB[0][0], SB[0][1] + fr[1]);
        vB1 = clipf(fop(fr[0], SB[0][0]) + SB[0][1]);
        vB2 = fop(SB[0][2], SB[0][3] + fr[3]);
        vB3 = clipf(fop(fr[2], SB[0][2]) + SB[0][3]);
        {
            int4 rkv = *(const int4*)&RK[t * 4];   // reload (saves live regs)
            if (rkv.x >= 0) { ob[rkv.x] = vA0; ob[rkv.x + INFO_LEN] = vB0; }
            if (rkv.y >= 0) { ob[rkv.y] = vA1; ob[rkv.y + INFO_LEN] = vB1; }
            if (rkv.z >= 0) { ob[rkv.z] = vA2; ob[rkv.z + INFO_LEN] = vB2; }
            if (rkv.w >= 0) { ob[rkv.w] = vA3; ob[rkv.w + INFO_LEN] = vB3; }
        }
        ob += obstride;
        // ===================== RIGHT pass (s = 0..8) =====================
        if (it != ITERS - 1) {
            RSTEP0(fr, SA[0]);         RSTEP0(fr, SB[0]);
            RSTEP1(SA[0], SA[1]);      RSTEP1(SB[0], SB[1]);
            CONV_W(SA[1], WBA, wW4, rW4);  CONV_W(SB[1], WBB, wW4, rW4);
            RSTEP0(SA[1], SA[2]);      RSTEP0(SB[1], SB[2]);
            RSTEP1(SA[2], SA[3]);      RSTEP1(SB[2], SB[3]);
            CONV_W(SA[3], WBA, wW2, rW2);  CONV_W(SB[3], WBB, wW2, rW2);
            RSTEP0(SA[3], SA[4]);      RSTEP0(SB[3], SB[4]);
            RSTEP1(SA[4], SA[5]);      RSTEP1(SB[4], SB[5]);
            CONV_W(SA[5], WBA, wW0, rW0);  CONV_W(SB[5], WBB, wW0, rW0);
            RSTEP0(SA[5], SA[6]);      RSTEP0(SB[5], SB[6]);
            RSTEP1(SA[6], SA[7]);      RSTEP1(SB[6], SB[7]);
            CONV_X2(SA[7], SB[7], XG0);    // (barrier)
            RSTEP0(SA[7], SA[8]);      RSTEP0(SB[7], SB[8]);
        }
    }
    // duplicate row: out[ITERS] = out[ITERS-1]
    {
        int4 rkv = *(const int4*)&RK[t * 4];
        if (rkv.x >= 0) { ob[rkv.x] = vA0; ob[rkv.x + INFO_LEN] = vB0; }
        if (rkv.y >= 0) { ob[rkv.y] = vA1; ob[rkv.y + INFO_LEN] = vB1; }
        if (rkv.z >= 0) { ob[rkv.z] = vA2; ob[rkv.z + INFO_LEN] = vB2; }
        if (rkv.w >= 0) { ob[rkv.w] = vA3; ob[rkv.w + INFO_LEN] = vB3; }
    }
}

extern "C" void kernel_launch(void* const* d_in, const int* in_sizes, int n_in,
                              void* d_out, int out_size, void* d_ws, size_t ws_size,
                              hipStream_t stream) {
    const float* rx   = (const float*)d_in[0];
    const int*   info = (const int*)d_in[1];
    float*       outp = (float*)d_out;
    polar_bp_r11<<<dim3(BATCH / 2), dim3(256), 0, stream>>>(rx, info, outp);
}